// Round 16
// baseline (278.936 us; speedup 1.0000x reference)
//
#include <hip/hip_runtime.h>
#include <math.h>

#define NPRED  25200
#define BATCH  16
#define NC     80
#define MAXDET 300
#define NDIM   87
#define NBIN   1024

// ---------------------------------------------------------------------------
// Workspace layout (bytes)
// ---------------------------------------------------------------------------
#define WS_SC      0                      // 16*25200*4   = 1,612,800
#define WS_BOX     1612800                // 16*25200*16  = 6,451,200
#define WS_SELIDX  8064000                // 16*300*4     = 19,200
#define WS_SELCNT  8083200                // 64
#define WS_HIST    8083264                // 16*1024*4    = 65,536
#define WS_CURSOR  8148800                // 65,536
#define WS_IA      8214336                // 65,536
#define WS_BINNED  8279872                // 16*25200*8   = 3,225,600

// ---------------------------------------------------------------------------
// Prep: LDS-staged coalesced loads; builds the per-image score-bin histogram.
// Class-max split across thread pairs (t, t+128). Validated rounds 11-15.
// ---------------------------------------------------------------------------
#define PREP_TPB 256
#define PB 128

__global__ __launch_bounds__(PREP_TPB)
void prep_kernel(const float* __restrict__ pred,
                 float* __restrict__ sc,
                 float4* __restrict__ box,
                 unsigned int* __restrict__ hist) {
    __shared__ float4 s4[PB * 85 / 4];
    __shared__ float sPart[PB];
    float* s = (float*)s4;
    const int t = threadIdx.x;
    const float4* p4 = (const float4*)(pred + (size_t)blockIdx.x * (PB * 85));
    for (int i = t; i < PB * 85 / 4; i += PREP_TPB) s4[i] = p4[i];
    __syncthreads();
    const int r = t & (PB - 1);
    const float* row = s + r * 85;
    const float obj = row[4];
    float part = -INFINITY;
    const int c0 = (t < PB) ? 0 : 40;
    #pragma unroll 8
    for (int c = c0; c < c0 + 40; ++c) {
        float v = __fmul_rn(row[5 + c], obj);
        if (v > part) part = v;
    }
    if (t >= PB) sPart[r] = part;
    __syncthreads();
    if (t < PB) {
        float best = fmaxf(part, sPart[r]);     // exact: max of same 80 products
        float x = row[0], y = row[1], w = row[2], h = row[3];
        float hw = __fmul_rn(w, 0.5f), hh = __fmul_rn(h, 0.5f);
        bool valid = (obj > 0.25f) && (best > 0.25f);
        int g = blockIdx.x * PB + t;
        sc[g]  = valid ? best : -INFINITY;
        box[g] = make_float4(__fsub_rn(x, hw), __fsub_rn(y, hh),
                             __fadd_rn(x, hw), __fadd_rn(y, hh));
        if (valid) {
            int img = g / NPRED;
            unsigned int sb = __float_as_uint(best);
            int bin = min((int)((sb - 0x3E800000u) >> 14), NBIN - 1);
            atomicAdd(&hist[img * NBIN + bin], 1u);
        }
    }
}

// ---------------------------------------------------------------------------
// Scan: per-image inclusive suffix-sum Ia[b] and per-bin cursors. Validated.
// ---------------------------------------------------------------------------
__global__ __launch_bounds__(NBIN)
void scan_kernel(const unsigned int* __restrict__ hist,
                 unsigned int* __restrict__ IaG,
                 unsigned int* __restrict__ cursor) {
    __shared__ unsigned int sA[NBIN], sB[NBIN];
    const int img = blockIdx.x, t = threadIdx.x;
    unsigned int cnt = hist[img * NBIN + t];
    sA[t] = cnt;
    __syncthreads();
    unsigned int *src = sA, *dst = sB;
    for (int d = 1; d < NBIN; d <<= 1) {
        dst[t] = src[t] + ((t + d) < NBIN ? src[t + d] : 0u);
        __syncthreads();
        unsigned int* tmp = src; src = dst; dst = tmp;
    }
    IaG[img * NBIN + t]    = src[t];
    cursor[img * NBIN + t] = src[t] - cnt;
}

// ---------------------------------------------------------------------------
// Scatter: counting-sort candidates by bin (u64 key = (~scorebits, index)).
// Within-bin order arbitrary here; binsort_kernel fixes it. Validated.
// ---------------------------------------------------------------------------
#define SCB  16
#define STPB 512

__global__ __launch_bounds__(STPB)
void scatter_kernel(const float* __restrict__ sc,
                    unsigned int* __restrict__ cursor,
                    unsigned long long* __restrict__ binned) {
    const int img = blockIdx.x / SCB, part = blockIdx.x % SCB;
    const float* sci = sc + (size_t)img * NPRED;
    for (int e = part * STPB + threadIdx.x; e < NPRED; e += SCB * STPB) {
        float s = sci[e];
        if (s != -INFINITY) {
            unsigned int sb = __float_as_uint(s);
            int bin = min((int)((sb - 0x3E800000u) >> 14), NBIN - 1);
            unsigned int pos = atomicAdd(&cursor[img * NBIN + bin], 1u);
            binned[(size_t)img * NPRED + pos] =
                ((unsigned long long)(~sb) << 32) | (unsigned int)e;
        }
    }
}

// ---------------------------------------------------------------------------
// Binsort: sort each bin's slice ascending by (~scorebits, index) -> the
// whole per-image binned array becomes globally sorted (score desc, idx asc).
// ONE WAVE per block. Validated rounds 13-15.
// ---------------------------------------------------------------------------
#define BS_TPB 64
#define BS_CAP 1024

__global__ __launch_bounds__(BS_TPB)
void binsort_kernel(const unsigned int* __restrict__ hist,
                    const unsigned int* __restrict__ IaG,
                    unsigned long long* __restrict__ binned) {
    __shared__ unsigned long long lds[BS_CAP];
    const int img = blockIdx.x >> 10, b = blockIdx.x & (NBIN - 1);
    const int t = threadIdx.x;
    const int cnt = (int)hist[img * NBIN + b];
    if (cnt <= 1) return;
    const int start = (int)IaG[img * NBIN + b] - cnt;
    unsigned long long* ptr = binned + (size_t)img * NPRED + start;

    if (cnt <= 64) {                       // single-wave shfl bitonic
        unsigned long long key = (t < cnt) ? ptr[t] : ~0ULL;
        #pragma unroll
        for (int k = 2; k <= 64; k <<= 1) {
            #pragma unroll
            for (int j = k >> 1; j > 0; j >>= 1) {
                unsigned long long other = __shfl_xor(key, j);
                bool up = ((t & k) == 0), lower = ((t & j) == 0);
                unsigned long long mn = min(key, other), mx = max(key, other);
                key = (up == lower) ? mn : mx;
            }
        }
        if (t < cnt) ptr[t] = key;
        return;
    }
    const int cap = min(cnt, BS_CAP);
    int m = 64; while (m < cap) m <<= 1;
    for (int i = t; i < m; i += BS_TPB) lds[i] = (i < cap) ? ptr[i] : ~0ULL;
    __syncthreads();
    for (int k = 2; k <= m; k <<= 1) {
        for (int j = k >> 1; j > 0; j >>= 1) {
            for (int i = t; i < m; i += BS_TPB) {
                int l = i ^ j;
                if (l > i) {
                    unsigned long long a = lds[i], b2 = lds[l];
                    if ((a > b2) == ((i & k) == 0)) { lds[i] = b2; lds[l] = a; }
                }
            }
            __syncthreads();
        }
    }
    for (int i = t; i < cap; i += BS_TPB) ptr[i] = lds[i];
}

// ---------------------------------------------------------------------------
// NMS, round-16: round-15 validated kernel with PAIRED KEEPS in the sweep:
// after keeping f1, the next pre-kill-alive candidate f2 (= ctz of the
// remaining ballot) is the TRUE next keep iff box1 does not suppress it
// (everything between f1 and f2 was already dead; kills commute). ~97% of
// iterations commit 2 keeps -> the serial ballot/shfl chain runs ~half as
// often; per-lane kill tests vs box1/box2 are independent (ILP). If box1
// kills f2, fall back to a single-keep iteration (exact). Sticky checked per
// keep in order. All other structure byte-identical to round 15.
// Exactly equivalent to repeated argmax+suppress: candidates in (score desc,
// index asc) order; kept iff no earlier-kept box IoU>0.45. IoU decision:
// fdiv_rn(i,d) > 0.45f  <=>  (double)i > K*(double)d, K=(double)0.45f+2^-26
// (0.45f mantissa even => midpoint rounds down; 26b x 24b f64 product exact).
// ---------------------------------------------------------------------------
#define TPB      1024
#define TCAP     4096
#define FIRSTCAP 1024
#define SLOTS    4                  // TCAP / TPB
#define NW       (TPB / 64)         // 16 waves

__device__ __forceinline__ bool iou_gt(float Bx1, float By1, float Bx2, float By2,
                                       float BA,
                                       float cx1, float cy1, float cx2, float cy2,
                                       float ca, double K) {
    float lx = fmaxf(Bx1, cx1), ly = fmaxf(By1, cy1);
    float rx = fminf(Bx2, cx2), ry = fminf(By2, cy2);
    float ww = fmaxf(__fsub_rn(rx, lx), 0.0f);
    float hh = fmaxf(__fsub_rn(ry, ly), 0.0f);
    float inter = __fmul_rn(ww, hh);
    float denom = __fadd_rn(__fsub_rn(__fadd_rn(BA, ca), inter), 1e-9f);
    return ((double)inter > K * (double)denom);
}

__device__ __forceinline__ int blk_min(int v, int* s_red, int t, int wid) {
    __syncthreads();                       // protect s_red reuse
    #pragma unroll
    for (int off = 32; off; off >>= 1) v = min(v, __shfl_down(v, off));
    if ((t & 63) == 0) s_red[wid] = v;
    __syncthreads();
    int r = s_red[0];
    #pragma unroll
    for (int w = 1; w < NW; ++w) r = min(r, s_red[w]);
    return r;
}

__global__ __launch_bounds__(TPB)
void nms_kernel(const unsigned long long* __restrict__ binned,
                const unsigned int* __restrict__ IaG,
                const float4* __restrict__ box_g,
                int* __restrict__ selidx,
                int* __restrict__ selcnt) {
    __shared__ unsigned long long sbuf[TCAP];   // 32 KB compacted sorted keys
    __shared__ unsigned int IaL[NBIN];          // 4 KB
    __shared__ float4 kbox[MAXDET];             // 4.8 KB
    __shared__ float  karea[MAXDET];            // 1.2 KB
    __shared__ unsigned char s_alive[TCAP];     // 4 KB
    __shared__ int s_red[NW];
    __shared__ unsigned int s_wsum[NW];
    __shared__ int s_kept, s_sticky, s_stickyIdx, s_fillFrom;

    const int img = blockIdx.x, t = threadIdx.x, wid = t >> 6, lane = t & 63;
    const float4* bxi = box_g + (size_t)img * NPRED;
    const unsigned long long* bin_img = binned + (size_t)img * NPRED;
    const double K = (double)0.45f + 0x1p-26;

    IaL[t] = IaG[img * NBIN + t];               // TPB == NBIN
    if (t == 0) { s_kept = 0; s_sticky = 0; }
    __syncthreads();
    const int n_valid = (int)IaL[0];

    int o = 0, b_hi = NBIN;
    bool firstT = true;
    for (;;) {
        __syncthreads();                        // publish s_kept/s_sticky
        if (s_kept >= MAXDET || s_sticky || o >= n_valid) break;   // uniform

        // ---- pick bin range [b_lo, b_hi): largest window <= cap ----
        const int cap = firstT ? FIRSTCAP : TCAP;
        int vb = (t < b_hi && ((int)IaL[t] - o) <= cap) ? t : 0x7FFFFFFF;
        int b_lo = blk_min(vb, s_red, t, wid);
        if (b_lo == 0x7FFFFFFF && cap != TCAP) {     // fallback: full cap
            vb = (t < b_hi && ((int)IaL[t] - o) <= TCAP) ? t : 0x7FFFFFFF;
            b_lo = blk_min(vb, s_red, t, wid);
        }
        int c;
        if (b_lo != 0x7FFFFFFF) {
            c = (int)IaL[b_lo] - o;
        } else {
            // single bin > TCAP: take its TOP TCAP (slice is sorted -> exact)
            vb = (t < b_hi && ((int)IaL[t] - o) > 0) ? -t : 0x7FFFFFFF;
            int m2 = blk_min(vb, s_red, t, wid);
            b_lo = -m2;
            c = min((int)IaL[b_lo] - o, TCAP);
        }
        if (c <= 0) break;

        const int kept0 = s_kept;               // uniform (post blk_min barriers)

        // ---- load own slots SLOT-MAJOR (pos = wid*S*64 + s*64 + lane),
        //      bulk-kill vs all kept (kills commute; CHUNKED x4),
        //      STABLE-compact into sbuf ----
        const int S = (c + 1023) >> 10;         // 1..4 slots/thread
        unsigned int um = 0;
        unsigned long long ukey[SLOTS];
        {
            float ux1[SLOTS], uy1[SLOTS], ux2[SLOTS], uy2[SLOTS], uar[SLOTS];
            #pragma unroll
            for (int s = 0; s < SLOTS; ++s) {
                int p = wid * (S << 6) + (s << 6) + lane;
                bool av = (s < S) && (p < c);
                unsigned long long key = av ? bin_img[o + p] : ~0ULL;
                ukey[s] = key;
                unsigned int ix = av ? (unsigned int)key : 0u;
                float4 b = bxi[ix];
                ux1[s] = b.x; uy1[s] = b.y; ux2[s] = b.z; uy2[s] = b.w;
                uar[s] = __fmul_rn(__fsub_rn(b.z, b.x), __fsub_rn(b.w, b.y));
                if (av) um |= (1u << s);
            }
            if (kept0 > 0 && um) {
                for (int kb = 0; kb < kept0 && um; kb += 4) {
                    float4 Bc[4]; float Ac[4];
                    #pragma unroll
                    for (int i = 0; i < 4; ++i) {
                        int j = kb + i; j = (j < kept0) ? j : kept0 - 1;
                        Bc[i] = kbox[j]; Ac[i] = karea[j];
                    }
                    #pragma unroll
                    for (int i = 0; i < 4; ++i) {
                        #pragma unroll
                        for (int s = 0; s < SLOTS; ++s) {
                            if (um & (1u << s)) {
                                if (iou_gt(Bc[i].x, Bc[i].y, Bc[i].z, Bc[i].w, Ac[i],
                                           ux1[s], uy1[s], ux2[s], uy2[s], uar[s], K))
                                    um &= ~(1u << s);
                            }
                        }
                    }
                }
            }
        }
        // stable compaction: rank = (wid, s, lane) = position order
        int myoff[SLOTS];
        unsigned int wcnt = 0;
        const unsigned long long lt = (lane == 0) ? 0ULL : (~0ULL >> (64 - lane));
        #pragma unroll
        for (int s = 0; s < SLOTS; ++s) {
            unsigned long long bal = __ballot((int)((um >> s) & 1u));
            myoff[s] = (int)(wcnt + __popcll(bal & lt));
            wcnt += (unsigned int)__popcll(bal);
        }
        if (lane == 0) s_wsum[wid] = wcnt;
        __syncthreads();
        int wbase = 0, cnt2 = 0;
        #pragma unroll
        for (int w = 0; w < NW; ++w) {
            int v = (int)s_wsum[w];
            if (w < wid) wbase += v;
            cnt2 += v;
        }
        #pragma unroll
        for (int s = 0; s < SLOTS; ++s)
            if (um & (1u << s)) sbuf[wbase + myoff[s]] = ukey[s];
        __syncthreads();

        if (cnt2 > 0) {
            // ---- unpack THREAD-MAJOR: thread t owns positions 4t..4t+3 ----
            unsigned int rm = 0;
            float rx1[SLOTS], ry1[SLOTS], rx2[SLOTS], ry2[SLOTS], rar[SLOTS];
            #pragma unroll
            for (int s = 0; s < SLOTS; ++s) {
                int p = t * SLOTS + s;
                bool av = (p < cnt2);
                unsigned int ix = av ? (unsigned int)sbuf[p] : 0u;
                float4 b = bxi[ix];
                rx1[s] = b.x; ry1[s] = b.y; rx2[s] = b.z; ry2[s] = b.w;
                rar[s] = __fmul_rn(__fsub_rn(b.z, b.x), __fsub_rn(b.w, b.y));
                if (av) rm |= (1u << s);
                s_alive[p] = av ? 1 : 0;
            }
            __syncthreads();

            const int nwin = (cnt2 + 63) >> 6;
            int applied = kept0;           // bulk-kill already covered [0,kept0)
            for (int g = 0; g < nwin; ++g) {
                int k0 = s_kept;           // uniform (post-barrier)
                // ---- phase-1: kill my candidates vs kept [applied,k0),
                //      CHUNKED x4 register preload. Writes s_alive ONLY for
                //      own slots (4t..4t+3). ----
                if (rm) {
                    for (int kb = applied; kb < k0 && rm; kb += 4) {
                        float4 Bc[4]; float Ac[4];
                        #pragma unroll
                        for (int i = 0; i < 4; ++i) {
                            int j = kb + i; j = (j < k0) ? j : k0 - 1;
                            Bc[i] = kbox[j]; Ac[i] = karea[j];
                        }
                        #pragma unroll
                        for (int i = 0; i < 4; ++i) {
                            #pragma unroll
                            for (int s = 0; s < SLOTS; ++s) {
                                if (rm & (1u << s)) {
                                    if (iou_gt(Bc[i].x, Bc[i].y, Bc[i].z, Bc[i].w, Ac[i],
                                               rx1[s], ry1[s], rx2[s], ry2[s], rar[s], K)) {
                                        rm &= ~(1u << s);
                                        s_alive[t * SLOTS + s] = 0;
                                    }
                                }
                            }
                        }
                    }
                }
                applied = k0;
                // ---- NO pre-sweep barrier: window g's s_alive entries are
                //      owned by threads [g*16,(g+1)*16) — all in wave g>>2,
                //      the wave that sweeps (same-wave LDS ops in-order). ----
                if (wid == (g >> 2)) {
                    int p = g * 64 + lane;
                    int a = s_alive[p];
                    unsigned int ix = a ? (unsigned int)sbuf[p] : 0u;
                    float4 b = bxi[ix];
                    float cx1 = b.x, cy1 = b.y, cx2 = b.z, cy2 = b.w;
                    float car = __fmul_rn(__fsub_rn(b.z, b.x), __fsub_rn(b.w, b.y));
                    int kept = k0;
                    for (;;) {
                        unsigned long long bal = __ballot(a != 0);
                        if (!bal) break;
                        const int f1 = (int)__builtin_ctzll(bal);
                        float A1x = __shfl(cx1, f1), A1y = __shfl(cy1, f1);
                        float A1z = __shfl(cx2, f1), A1w = __shfl(cy2, f1);
                        float AA1 = __shfl(car, f1);
                        int   id1 = __shfl((int)ix, f1);
                        if (lane == f1) a = 0;
                        if (lane == 0) {
                            selidx[img * MAXDET + kept] = id1;
                            kbox[kept] = make_float4(A1x, A1y, A1z, A1w);
                            karea[kept] = AA1;
                        }
                        // sticky check: reference-exact self-IoU (pure f64)
                        float dns1 = __fadd_rn(__fsub_rn(__fadd_rn(AA1, AA1), AA1), 1e-9f);
                        if (!((double)AA1 > K * (double)dns1)) {
                            if (lane == 0) { s_sticky = 1; s_stickyIdx = id1; s_fillFrom = kept + 1; }
                            kept = MAXDET;
                            break;
                        }
                        ++kept;
                        if (kept >= MAXDET) break;
                        // ---- paired second keep: f2 = first alive after f1
                        //      (pre-kill); true next keep iff box1 does not
                        //      suppress it (uniform test). ----
                        bool two = false;
                        float A2x = 0, A2y = 0, A2z = 0, A2w = 0, AA2 = 0;
                        unsigned long long bal2 = bal & ~(1ULL << f1);
                        if (bal2) {
                            const int f2 = (int)__builtin_ctzll(bal2);
                            A2x = __shfl(cx1, f2); A2y = __shfl(cy1, f2);
                            A2z = __shfl(cx2, f2); A2w = __shfl(cy2, f2);
                            AA2 = __shfl(car, f2);
                            int id2 = __shfl((int)ix, f2);
                            if (!iou_gt(A1x, A1y, A1z, A1w, AA1,
                                        A2x, A2y, A2z, A2w, AA2, K)) {
                                if (lane == f2) a = 0;
                                if (lane == 0) {
                                    selidx[img * MAXDET + kept] = id2;
                                    kbox[kept] = make_float4(A2x, A2y, A2z, A2w);
                                    karea[kept] = AA2;
                                }
                                float dns2 = __fadd_rn(__fsub_rn(__fadd_rn(AA2, AA2), AA2), 1e-9f);
                                if (!((double)AA2 > K * (double)dns2)) {
                                    if (lane == 0) { s_sticky = 1; s_stickyIdx = id2; s_fillFrom = kept + 1; }
                                    kept = MAXDET;
                                    break;
                                }
                                ++kept;
                                two = true;
                            }
                        }
                        // apply kills to own candidate (box1, and box2 if kept)
                        if (a) {
                            if (iou_gt(A1x, A1y, A1z, A1w, AA1,
                                       cx1, cy1, cx2, cy2, car, K)) a = 0;
                        }
                        if (two && a) {
                            if (iou_gt(A2x, A2y, A2z, A2w, AA2,
                                       cx1, cy1, cx2, cy2, car, K)) a = 0;
                        }
                        if (kept >= MAXDET) break;
                    }
                    if (lane == 0) s_kept = kept;
                }
                __syncthreads();               // publish kbox/karea/s_kept
                if (((t * SLOTS) >> 6) == g) rm = 0;       // my window swept
                if (s_kept >= MAXDET || s_sticky) break;   // uniform
            }
        }
        o += c;
        if (o >= (int)IaL[b_lo]) b_hi = b_lo;
        firstT = false;
    }
    // ---- finalize ----
    int keptF = s_kept;
    if (s_sticky) {
        for (int k2 = s_fillFrom + t; k2 < MAXDET; k2 += TPB)
            selidx[img * MAXDET + k2] = s_stickyIdx;
        keptF = MAXDET;
    }
    if (t == 0) selcnt[img] = keptF;
}

// ---------------------------------------------------------------------------
// Gather: writes every output element (zeros for padding rows — no memset
// needed). conf/cls/obj recomputed from pred with the identical rn ops.
// ---------------------------------------------------------------------------
#define GT 256

__global__ __launch_bounds__(GT)
void gather_kernel(const float* __restrict__ pred,
                   const float4* __restrict__ box,
                   const float* __restrict__ logits,
                   const int* __restrict__ selidx,
                   const int* __restrict__ selcnt,
                   float* __restrict__ out) {
    int tid = blockIdx.x * GT + threadIdx.x;
    if (tid >= BATCH * MAXDET * NDIM) return;
    int row = tid / NDIM, col = tid - row * NDIM;
    int img = row / MAXDET, det = row - img * MAXDET;
    float v = 0.0f;
    if (det < selcnt[img]) {
        int s = selidx[img * MAXDET + det];
        size_t g = (size_t)img * NPRED + s;
        if (col < 4) {
            float4 b = box[g];
            v = (col == 0) ? b.x : (col == 1) ? b.y : (col == 2) ? b.z : b.w;
        } else if (col == 6) {
            v = pred[g * 85 + 4];
        } else if (col >= 7) {
            v = logits[g * NC + (col - 7)];
        } else {
            const float* p = pred + g * 85;
            float obj = p[4];
            float best = -INFINITY; int bc = 0;
            #pragma unroll 8
            for (int c = 0; c < NC; ++c) {
                float q = __fmul_rn(p[5 + c], obj);
                if (q > best) { best = q; bc = c; }
            }
            v = (col == 4) ? best : (float)bc;
        }
    }
    out[tid] = v;
}

extern "C" void kernel_launch(void* const* d_in, const int* in_sizes, int n_in,
                              void* d_out, int out_size, void* d_ws, size_t ws_size,
                              hipStream_t stream) {
    const float* pred   = (const float*)d_in[0];
    const float* logits = (const float*)d_in[1];
    float* out = (float*)d_out;

    char* ws = (char*)d_ws;
    float*              sc     = (float*)(ws + WS_SC);
    float4*             box    = (float4*)(ws + WS_BOX);
    int*                selidx = (int*)(ws + WS_SELIDX);
    int*                selcnt = (int*)(ws + WS_SELCNT);
    unsigned int*       hist   = (unsigned int*)(ws + WS_HIST);
    unsigned int*       cursor = (unsigned int*)(ws + WS_CURSOR);
    unsigned int*       IaG    = (unsigned int*)(ws + WS_IA);
    unsigned long long* binned = (unsigned long long*)(ws + WS_BINNED);

    hipMemsetAsync(hist, 0, BATCH * NBIN * sizeof(unsigned int), stream);

    prep_kernel<<<BATCH * NPRED / PB, PREP_TPB, 0, stream>>>(pred, sc, box, hist);
    scan_kernel<<<BATCH, NBIN, 0, stream>>>(hist, IaG, cursor);
    scatter_kernel<<<BATCH * SCB, STPB, 0, stream>>>(sc, cursor, binned);
    binsort_kernel<<<BATCH * NBIN, BS_TPB, 0, stream>>>(hist, IaG, binned);
    nms_kernel<<<BATCH, TPB, 0, stream>>>(binned, IaG, box, selidx, selcnt);
    int gtot = BATCH * MAXDET * NDIM;
    gather_kernel<<<(gtot + GT - 1) / GT, GT, 0, stream>>>(pred, box, logits, selidx, selcnt, out);
}

// Round 17
// 264.989 us; speedup vs baseline: 1.0526x; 1.0526x over previous
//
#include <hip/hip_runtime.h>
#include <math.h>

#define NPRED  25200
#define BATCH  16
#define NC     80
#define MAXDET 300
#define NDIM   87
#define NBIN   1024

// ---------------------------------------------------------------------------
// Workspace layout (bytes)
// ---------------------------------------------------------------------------
#define WS_SC      0                      // 16*25200*4   = 1,612,800
#define WS_BOX     1612800                // 16*25200*16  = 6,451,200
#define WS_SELIDX  8064000                // 16*300*4     = 19,200
#define WS_SELCNT  8083200                // 64
#define WS_HIST    8083264                // 16*1024*4    = 65,536
#define WS_CURSOR  8148800                // 65,536
#define WS_IA      8214336                // 65,536
#define WS_BINNED  8279872                // 16*25200*8   = 3,225,600

// ---------------------------------------------------------------------------
// Prep: LDS-staged coalesced loads; builds the per-image score-bin histogram.
// Class-max split across thread pairs (t, t+128). Validated rounds 11-15.
// ---------------------------------------------------------------------------
#define PREP_TPB 256
#define PB 128

__global__ __launch_bounds__(PREP_TPB)
void prep_kernel(const float* __restrict__ pred,
                 float* __restrict__ sc,
                 float4* __restrict__ box,
                 unsigned int* __restrict__ hist) {
    __shared__ float4 s4[PB * 85 / 4];
    __shared__ float sPart[PB];
    float* s = (float*)s4;
    const int t = threadIdx.x;
    const float4* p4 = (const float4*)(pred + (size_t)blockIdx.x * (PB * 85));
    for (int i = t; i < PB * 85 / 4; i += PREP_TPB) s4[i] = p4[i];
    __syncthreads();
    const int r = t & (PB - 1);
    const float* row = s + r * 85;
    const float obj = row[4];
    float part = -INFINITY;
    const int c0 = (t < PB) ? 0 : 40;
    #pragma unroll 8
    for (int c = c0; c < c0 + 40; ++c) {
        float v = __fmul_rn(row[5 + c], obj);
        if (v > part) part = v;
    }
    if (t >= PB) sPart[r] = part;
    __syncthreads();
    if (t < PB) {
        float best = fmaxf(part, sPart[r]);     // exact: max of same 80 products
        float x = row[0], y = row[1], w = row[2], h = row[3];
        float hw = __fmul_rn(w, 0.5f), hh = __fmul_rn(h, 0.5f);
        bool valid = (obj > 0.25f) && (best > 0.25f);
        int g = blockIdx.x * PB + t;
        sc[g]  = valid ? best : -INFINITY;
        box[g] = make_float4(__fsub_rn(x, hw), __fsub_rn(y, hh),
                             __fadd_rn(x, hw), __fadd_rn(y, hh));
        if (valid) {
            int img = g / NPRED;
            unsigned int sb = __float_as_uint(best);
            int bin = min((int)((sb - 0x3E800000u) >> 14), NBIN - 1);
            atomicAdd(&hist[img * NBIN + bin], 1u);
        }
    }
}

// ---------------------------------------------------------------------------
// Scan: per-image inclusive suffix-sum Ia[b] and per-bin cursors. Validated.
// ---------------------------------------------------------------------------
__global__ __launch_bounds__(NBIN)
void scan_kernel(const unsigned int* __restrict__ hist,
                 unsigned int* __restrict__ IaG,
                 unsigned int* __restrict__ cursor) {
    __shared__ unsigned int sA[NBIN], sB[NBIN];
    const int img = blockIdx.x, t = threadIdx.x;
    unsigned int cnt = hist[img * NBIN + t];
    sA[t] = cnt;
    __syncthreads();
    unsigned int *src = sA, *dst = sB;
    for (int d = 1; d < NBIN; d <<= 1) {
        dst[t] = src[t] + ((t + d) < NBIN ? src[t + d] : 0u);
        __syncthreads();
        unsigned int* tmp = src; src = dst; dst = tmp;
    }
    IaG[img * NBIN + t]    = src[t];
    cursor[img * NBIN + t] = src[t] - cnt;
}

// ---------------------------------------------------------------------------
// Scatter: counting-sort candidates by bin (u64 key = (~scorebits, index)).
// Within-bin order arbitrary here; binsort_kernel fixes it. Validated.
// ---------------------------------------------------------------------------
#define SCB  16
#define STPB 512

__global__ __launch_bounds__(STPB)
void scatter_kernel(const float* __restrict__ sc,
                    unsigned int* __restrict__ cursor,
                    unsigned long long* __restrict__ binned) {
    const int img = blockIdx.x / SCB, part = blockIdx.x % SCB;
    const float* sci = sc + (size_t)img * NPRED;
    for (int e = part * STPB + threadIdx.x; e < NPRED; e += SCB * STPB) {
        float s = sci[e];
        if (s != -INFINITY) {
            unsigned int sb = __float_as_uint(s);
            int bin = min((int)((sb - 0x3E800000u) >> 14), NBIN - 1);
            unsigned int pos = atomicAdd(&cursor[img * NBIN + bin], 1u);
            binned[(size_t)img * NPRED + pos] =
                ((unsigned long long)(~sb) << 32) | (unsigned int)e;
        }
    }
}

// ---------------------------------------------------------------------------
// Binsort: sort each bin's slice ascending by (~scorebits, index) -> the
// whole per-image binned array becomes globally sorted (score desc, idx asc).
// ONE WAVE per block. Validated rounds 13-15.
// ---------------------------------------------------------------------------
#define BS_TPB 64
#define BS_CAP 1024

__global__ __launch_bounds__(BS_TPB)
void binsort_kernel(const unsigned int* __restrict__ hist,
                    const unsigned int* __restrict__ IaG,
                    unsigned long long* __restrict__ binned) {
    __shared__ unsigned long long lds[BS_CAP];
    const int img = blockIdx.x >> 10, b = blockIdx.x & (NBIN - 1);
    const int t = threadIdx.x;
    const int cnt = (int)hist[img * NBIN + b];
    if (cnt <= 1) return;
    const int start = (int)IaG[img * NBIN + b] - cnt;
    unsigned long long* ptr = binned + (size_t)img * NPRED + start;

    if (cnt <= 64) {                       // single-wave shfl bitonic
        unsigned long long key = (t < cnt) ? ptr[t] : ~0ULL;
        #pragma unroll
        for (int k = 2; k <= 64; k <<= 1) {
            #pragma unroll
            for (int j = k >> 1; j > 0; j >>= 1) {
                unsigned long long other = __shfl_xor(key, j);
                bool up = ((t & k) == 0), lower = ((t & j) == 0);
                unsigned long long mn = min(key, other), mx = max(key, other);
                key = (up == lower) ? mn : mx;
            }
        }
        if (t < cnt) ptr[t] = key;
        return;
    }
    const int cap = min(cnt, BS_CAP);
    int m = 64; while (m < cap) m <<= 1;
    for (int i = t; i < m; i += BS_TPB) lds[i] = (i < cap) ? ptr[i] : ~0ULL;
    __syncthreads();
    for (int k = 2; k <= m; k <<= 1) {
        for (int j = k >> 1; j > 0; j >>= 1) {
            for (int i = t; i < m; i += BS_TPB) {
                int l = i ^ j;
                if (l > i) {
                    unsigned long long a = lds[i], b2 = lds[l];
                    if ((a > b2) == ((i & k) == 0)) { lds[i] = b2; lds[l] = a; }
                }
            }
            __syncthreads();
        }
    }
    for (int i = t; i < cap; i += BS_TPB) ptr[i] = lds[i];
}

// ---------------------------------------------------------------------------
// NMS — round-15 kernel VERBATIM (session-best validated: nms ~186 us,
// total ~265 us). Pre-sorted binned candidates; per tranche: slot-major
// load, bulk-kill vs all kept (kills commute; CHUNKED x4 register preload),
// STABLE ballot/popcount compaction, thread-major unpack + s_alive, then
// per-64-window {block-parallel phase-1 chunked kills, owner-wave
// ballot/ctz/shfl serial sweep with NO pre-sweep barrier (s_alive entries
// for window g are owned by threads of wave g>>2 — same-wave LDS ops are
// in-order)}. End-of-window barrier publishes kbox/karea/s_kept.
// Exactly equivalent to repeated argmax+suppress: candidates in (score desc,
// index asc) order; kept iff no earlier-kept box IoU>0.45. Sticky degenerate
// case (kept box with self-IoU<=0.45 re-selected for all remaining slots)
// handled exactly. IoU decision exact:
// fdiv_rn(i,d) > 0.45f  <=>  (double)i > K*(double)d, K=(double)0.45f+2^-26
// (0.45f mantissa even => midpoint rounds down; 26b x 24b f64 product exact).
// [Falsified & excluded: r12 f32-band (+f64-issue theory wrong), r13
// wave-owned 256-windows, r16 paired keeps — all regressed vs this config.]
// ---------------------------------------------------------------------------
#define TPB      1024
#define TCAP     4096
#define FIRSTCAP 1024
#define SLOTS    4                  // TCAP / TPB
#define NW       (TPB / 64)         // 16 waves

__device__ __forceinline__ bool iou_gt(float Bx1, float By1, float Bx2, float By2,
                                       float BA,
                                       float cx1, float cy1, float cx2, float cy2,
                                       float ca, double K) {
    float lx = fmaxf(Bx1, cx1), ly = fmaxf(By1, cy1);
    float rx = fminf(Bx2, cx2), ry = fminf(By2, cy2);
    float ww = fmaxf(__fsub_rn(rx, lx), 0.0f);
    float hh = fmaxf(__fsub_rn(ry, ly), 0.0f);
    float inter = __fmul_rn(ww, hh);
    float denom = __fadd_rn(__fsub_rn(__fadd_rn(BA, ca), inter), 1e-9f);
    return ((double)inter > K * (double)denom);
}

__device__ __forceinline__ int blk_min(int v, int* s_red, int t, int wid) {
    __syncthreads();                       // protect s_red reuse
    #pragma unroll
    for (int off = 32; off; off >>= 1) v = min(v, __shfl_down(v, off));
    if ((t & 63) == 0) s_red[wid] = v;
    __syncthreads();
    int r = s_red[0];
    #pragma unroll
    for (int w = 1; w < NW; ++w) r = min(r, s_red[w]);
    return r;
}

__global__ __launch_bounds__(TPB)
void nms_kernel(const unsigned long long* __restrict__ binned,
                const unsigned int* __restrict__ IaG,
                const float4* __restrict__ box_g,
                int* __restrict__ selidx,
                int* __restrict__ selcnt) {
    __shared__ unsigned long long sbuf[TCAP];   // 32 KB compacted sorted keys
    __shared__ unsigned int IaL[NBIN];          // 4 KB
    __shared__ float4 kbox[MAXDET];             // 4.8 KB
    __shared__ float  karea[MAXDET];            // 1.2 KB
    __shared__ unsigned char s_alive[TCAP];     // 4 KB
    __shared__ int s_red[NW];
    __shared__ unsigned int s_wsum[NW];
    __shared__ int s_kept, s_sticky, s_stickyIdx, s_fillFrom;

    const int img = blockIdx.x, t = threadIdx.x, wid = t >> 6, lane = t & 63;
    const float4* bxi = box_g + (size_t)img * NPRED;
    const unsigned long long* bin_img = binned + (size_t)img * NPRED;
    const double K = (double)0.45f + 0x1p-26;

    IaL[t] = IaG[img * NBIN + t];               // TPB == NBIN
    if (t == 0) { s_kept = 0; s_sticky = 0; }
    __syncthreads();
    const int n_valid = (int)IaL[0];

    int o = 0, b_hi = NBIN;
    bool firstT = true;
    for (;;) {
        __syncthreads();                        // publish s_kept/s_sticky
        if (s_kept >= MAXDET || s_sticky || o >= n_valid) break;   // uniform

        // ---- pick bin range [b_lo, b_hi): largest window <= cap ----
        const int cap = firstT ? FIRSTCAP : TCAP;
        int vb = (t < b_hi && ((int)IaL[t] - o) <= cap) ? t : 0x7FFFFFFF;
        int b_lo = blk_min(vb, s_red, t, wid);
        if (b_lo == 0x7FFFFFFF && cap != TCAP) {     // fallback: full cap
            vb = (t < b_hi && ((int)IaL[t] - o) <= TCAP) ? t : 0x7FFFFFFF;
            b_lo = blk_min(vb, s_red, t, wid);
        }
        int c;
        if (b_lo != 0x7FFFFFFF) {
            c = (int)IaL[b_lo] - o;
        } else {
            // single bin > TCAP: take its TOP TCAP (slice is sorted -> exact)
            vb = (t < b_hi && ((int)IaL[t] - o) > 0) ? -t : 0x7FFFFFFF;
            int m2 = blk_min(vb, s_red, t, wid);
            b_lo = -m2;
            c = min((int)IaL[b_lo] - o, TCAP);
        }
        if (c <= 0) break;

        const int kept0 = s_kept;               // uniform (post blk_min barriers)

        // ---- load own slots SLOT-MAJOR (pos = wid*S*64 + s*64 + lane),
        //      bulk-kill vs all kept (kills commute; CHUNKED x4),
        //      STABLE-compact into sbuf ----
        const int S = (c + 1023) >> 10;         // 1..4 slots/thread
        unsigned int um = 0;
        unsigned long long ukey[SLOTS];
        {
            float ux1[SLOTS], uy1[SLOTS], ux2[SLOTS], uy2[SLOTS], uar[SLOTS];
            #pragma unroll
            for (int s = 0; s < SLOTS; ++s) {
                int p = wid * (S << 6) + (s << 6) + lane;
                bool av = (s < S) && (p < c);
                unsigned long long key = av ? bin_img[o + p] : ~0ULL;
                ukey[s] = key;
                unsigned int ix = av ? (unsigned int)key : 0u;
                float4 b = bxi[ix];
                ux1[s] = b.x; uy1[s] = b.y; ux2[s] = b.z; uy2[s] = b.w;
                uar[s] = __fmul_rn(__fsub_rn(b.z, b.x), __fsub_rn(b.w, b.y));
                if (av) um |= (1u << s);
            }
            if (kept0 > 0 && um) {
                for (int kb = 0; kb < kept0 && um; kb += 4) {
                    float4 Bc[4]; float Ac[4];
                    #pragma unroll
                    for (int i = 0; i < 4; ++i) {
                        int j = kb + i; j = (j < kept0) ? j : kept0 - 1;
                        Bc[i] = kbox[j]; Ac[i] = karea[j];
                    }
                    #pragma unroll
                    for (int i = 0; i < 4; ++i) {
                        #pragma unroll
                        for (int s = 0; s < SLOTS; ++s) {
                            if (um & (1u << s)) {
                                if (iou_gt(Bc[i].x, Bc[i].y, Bc[i].z, Bc[i].w, Ac[i],
                                           ux1[s], uy1[s], ux2[s], uy2[s], uar[s], K))
                                    um &= ~(1u << s);
                            }
                        }
                    }
                }
            }
        }
        // stable compaction: rank = (wid, s, lane) = position order
        int myoff[SLOTS];
        unsigned int wcnt = 0;
        const unsigned long long lt = (lane == 0) ? 0ULL : (~0ULL >> (64 - lane));
        #pragma unroll
        for (int s = 0; s < SLOTS; ++s) {
            unsigned long long bal = __ballot((int)((um >> s) & 1u));
            myoff[s] = (int)(wcnt + __popcll(bal & lt));
            wcnt += (unsigned int)__popcll(bal);
        }
        if (lane == 0) s_wsum[wid] = wcnt;
        __syncthreads();
        int wbase = 0, cnt2 = 0;
        #pragma unroll
        for (int w = 0; w < NW; ++w) {
            int v = (int)s_wsum[w];
            if (w < wid) wbase += v;
            cnt2 += v;
        }
        #pragma unroll
        for (int s = 0; s < SLOTS; ++s)
            if (um & (1u << s)) sbuf[wbase + myoff[s]] = ukey[s];
        __syncthreads();

        if (cnt2 > 0) {
            // ---- unpack THREAD-MAJOR: thread t owns positions 4t..4t+3 ----
            unsigned int rm = 0;
            float rx1[SLOTS], ry1[SLOTS], rx2[SLOTS], ry2[SLOTS], rar[SLOTS];
            #pragma unroll
            for (int s = 0; s < SLOTS; ++s) {
                int p = t * SLOTS + s;
                bool av = (p < cnt2);
                unsigned int ix = av ? (unsigned int)sbuf[p] : 0u;
                float4 b = bxi[ix];
                rx1[s] = b.x; ry1[s] = b.y; rx2[s] = b.z; ry2[s] = b.w;
                rar[s] = __fmul_rn(__fsub_rn(b.z, b.x), __fsub_rn(b.w, b.y));
                if (av) rm |= (1u << s);
                s_alive[p] = av ? 1 : 0;
            }
            __syncthreads();

            const int nwin = (cnt2 + 63) >> 6;
            int applied = kept0;           // bulk-kill already covered [0,kept0)
            for (int g = 0; g < nwin; ++g) {
                int k0 = s_kept;           // uniform (post-barrier)
                // ---- phase-1: kill my candidates vs kept [applied,k0),
                //      CHUNKED x4 register preload. Writes s_alive ONLY for
                //      own slots (4t..4t+3). ----
                if (rm) {
                    for (int kb = applied; kb < k0 && rm; kb += 4) {
                        float4 Bc[4]; float Ac[4];
                        #pragma unroll
                        for (int i = 0; i < 4; ++i) {
                            int j = kb + i; j = (j < k0) ? j : k0 - 1;
                            Bc[i] = kbox[j]; Ac[i] = karea[j];
                        }
                        #pragma unroll
                        for (int i = 0; i < 4; ++i) {
                            #pragma unroll
                            for (int s = 0; s < SLOTS; ++s) {
                                if (rm & (1u << s)) {
                                    if (iou_gt(Bc[i].x, Bc[i].y, Bc[i].z, Bc[i].w, Ac[i],
                                               rx1[s], ry1[s], rx2[s], ry2[s], rar[s], K)) {
                                        rm &= ~(1u << s);
                                        s_alive[t * SLOTS + s] = 0;
                                    }
                                }
                            }
                        }
                    }
                }
                applied = k0;
                // ---- NO barrier: window g's s_alive entries are owned by
                //      threads [g*16,(g+1)*16) — all in wave g>>2, which is
                //      the wave that sweeps. Same-wave LDS ops are in-order,
                //      so the sweep sees its own phase-1 writes. ----
                if (wid == (g >> 2)) {
                    int p = g * 64 + lane;
                    int a = s_alive[p];
                    unsigned int ix = a ? (unsigned int)sbuf[p] : 0u;
                    float4 b = bxi[ix];
                    float cx1 = b.x, cy1 = b.y, cx2 = b.z, cy2 = b.w;
                    float car = __fmul_rn(__fsub_rn(b.z, b.x), __fsub_rn(b.w, b.y));
                    int kept = k0;
                    for (;;) {
                        unsigned long long bal = __ballot(a != 0);
                        if (!bal) break;
                        int f = (int)__builtin_ctzll(bal);
                        float Bx1 = __shfl(cx1, f), By1 = __shfl(cy1, f);
                        float Bx2 = __shfl(cx2, f), By2 = __shfl(cy2, f);
                        float BA  = __shfl(car, f);
                        int bidx  = __shfl((int)ix, f);
                        if (lane == f) a = 0;
                        if (lane == 0) {
                            selidx[img * MAXDET + kept] = bidx;
                            kbox[kept] = make_float4(Bx1, By1, Bx2, By2);
                            karea[kept] = BA;
                        }
                        // sticky check: reference-exact self-IoU (pure f64)
                        float dns = __fadd_rn(__fsub_rn(__fadd_rn(BA, BA), BA), 1e-9f);
                        if (!((double)BA > K * (double)dns)) {
                            if (lane == 0) { s_sticky = 1; s_stickyIdx = bidx; s_fillFrom = kept + 1; }
                            kept = MAXDET;
                            break;
                        }
                        if (a) {
                            if (iou_gt(Bx1, By1, Bx2, By2, BA,
                                       cx1, cy1, cx2, cy2, car, K)) a = 0;
                        }
                        ++kept;
                        if (kept >= MAXDET) break;
                    }
                    if (lane == 0) s_kept = kept;
                }
                __syncthreads();               // publish kbox/karea/s_kept
                if (((t * SLOTS) >> 6) == g) rm = 0;       // my window swept
                if (s_kept >= MAXDET || s_sticky) break;   // uniform
            }
        }
        o += c;
        if (o >= (int)IaL[b_lo]) b_hi = b_lo;
        firstT = false;
    }
    // ---- finalize ----
    int keptF = s_kept;
    if (s_sticky) {
        for (int k2 = s_fillFrom + t; k2 < MAXDET; k2 += TPB)
            selidx[img * MAXDET + k2] = s_stickyIdx;
        keptF = MAXDET;
    }
    if (t == 0) selcnt[img] = keptF;
}

// ---------------------------------------------------------------------------
// Gather: writes every output element (zeros for padding rows — no memset
// needed). conf/cls/obj recomputed from pred with the identical rn ops.
// ---------------------------------------------------------------------------
#define GT 256

__global__ __launch_bounds__(GT)
void gather_kernel(const float* __restrict__ pred,
                   const float4* __restrict__ box,
                   const float* __restrict__ logits,
                   const int* __restrict__ selidx,
                   const int* __restrict__ selcnt,
                   float* __restrict__ out) {
    int tid = blockIdx.x * GT + threadIdx.x;
    if (tid >= BATCH * MAXDET * NDIM) return;
    int row = tid / NDIM, col = tid - row * NDIM;
    int img = row / MAXDET, det = row - img * MAXDET;
    float v = 0.0f;
    if (det < selcnt[img]) {
        int s = selidx[img * MAXDET + det];
        size_t g = (size_t)img * NPRED + s;
        if (col < 4) {
            float4 b = box[g];
            v = (col == 0) ? b.x : (col == 1) ? b.y : (col == 2) ? b.z : b.w;
        } else if (col == 6) {
            v = pred[g * 85 + 4];
        } else if (col >= 7) {
            v = logits[g * NC + (col - 7)];
        } else {
            const float* p = pred + g * 85;
            float obj = p[4];
            float best = -INFINITY; int bc = 0;
            #pragma unroll 8
            for (int c = 0; c < NC; ++c) {
                float q = __fmul_rn(p[5 + c], obj);
                if (q > best) { best = q; bc = c; }
            }
            v = (col == 4) ? best : (float)bc;
        }
    }
    out[tid] = v;
}

extern "C" void kernel_launch(void* const* d_in, const int* in_sizes, int n_in,
                              void* d_out, int out_size, void* d_ws, size_t ws_size,
                              hipStream_t stream) {
    const float* pred   = (const float*)d_in[0];
    const float* logits = (const float*)d_in[1];
    float* out = (float*)d_out;

    char* ws = (char*)d_ws;
    float*              sc     = (float*)(ws + WS_SC);
    float4*             box    = (float4*)(ws + WS_BOX);
    int*                selidx = (int*)(ws + WS_SELIDX);
    int*                selcnt = (int*)(ws + WS_SELCNT);
    unsigned int*       hist   = (unsigned int*)(ws + WS_HIST);
    unsigned int*       cursor = (unsigned int*)(ws + WS_CURSOR);
    unsigned int*       IaG    = (unsigned int*)(ws + WS_IA);
    unsigned long long* binned = (unsigned long long*)(ws + WS_BINNED);

    hipMemsetAsync(hist, 0, BATCH * NBIN * sizeof(unsigned int), stream);

    prep_kernel<<<BATCH * NPRED / PB, PREP_TPB, 0, stream>>>(pred, sc, box, hist);
    scan_kernel<<<BATCH, NBIN, 0, stream>>>(hist, IaG, cursor);
    scatter_kernel<<<BATCH * SCB, STPB, 0, stream>>>(sc, cursor, binned);
    binsort_kernel<<<BATCH * NBIN, BS_TPB, 0, stream>>>(hist, IaG, binned);
    nms_kernel<<<BATCH, TPB, 0, stream>>>(binned, IaG, box, selidx, selcnt);
    int gtot = BATCH * MAXDET * NDIM;
    gather_kernel<<<(gtot + GT - 1) / GT, GT, 0, stream>>>(pred, box, logits, selidx, selcnt, out);
}